// Round 10
// baseline (125.163 us; speedup 1.0000x reference)
//
#include <hip/hip_runtime.h>
#include <math.h>

#define NC 16
#define DIM 16
#define LAYERS 6

typedef float v2f __attribute__((ext_vector_type(2)));

// ws layout (floats)
#define WS_LINV  0      // [NC][DIM][DIM] row-major, zeros above diag, 4096
#define WS_MU2   4096   // [NC][DIM] = Linv_c * mean_c, 256
#define WS_CST   4352   // [NC], 16
#define WS_ALPHA 4368   // [L][NC] = exp(log_alpha), 96
#define WS_TOT   4464

// One block per component, one wave per block (R6 version, kept).
__global__ void __launch_bounds__(64) prep_kernel(
    const float* __restrict__ cov, const float* __restrict__ log_alpha,
    const float* __restrict__ mean, float* __restrict__ ws) {
    __shared__ float A[DIM * 17];     // padded: A[i][j] at i*17+j
    __shared__ float B[DIM * DIM];    // Linv staged for mu2 matvec
    const int c = blockIdx.x;
    const int t = threadIdx.x;        // 0..63
    for (int k = t; k < DIM * DIM; k += 64) {
        int r = k >> 4, j = k & 15;
        A[r * 17 + j] = cov[c * 256 + k];
    }
    __syncthreads();
    const int i = t & 15;
    const bool act = t < 16;
    for (int k = 0; k < DIM; ++k) {
        if (act && i == k) A[k * 17 + k] = sqrtf(A[k * 17 + k]);
        __syncthreads();
        if (act && i > k) A[i * 17 + k] /= A[k * 17 + k];
        __syncthreads();
        if (act && i > k) {
            float lik = A[i * 17 + k];
            for (int j2 = k + 1; j2 <= i; ++j2)
                A[i * 17 + j2] -= lik * A[j2 * 17 + k];
        }
        __syncthreads();
    }
    // Forward substitution for column j of Linv — fully unrolled (VGPRs).
    const int j = i;
    float x[DIM];
    #pragma unroll
    for (int r = 0; r < DIM; ++r) {
        float s = (r == j) ? 1.0f : 0.0f;
        #pragma unroll
        for (int k = 0; k < r; ++k) s = fmaf(-A[r * 17 + k], x[k], s);
        x[r] = s / A[r * 17 + r];
    }
    if (act) {
        #pragma unroll
        for (int r = 0; r < DIM; ++r) {
            B[r * 16 + j] = x[r];
            ws[WS_LINV + c * 256 + r * 16 + j] = x[r];   // 0 above diag
        }
    }
    __syncthreads();
    if (t == 0) {
        float hld = 0.0f;
        #pragma unroll
        for (int r = 0; r < DIM; ++r) hld += __logf(A[r * 17 + r]);
        const float log2pi = 1.8378770664093453f;
        ws[WS_CST + c] = -0.5f * (float)DIM * log2pi - hld;
    }
    if (t < LAYERS) ws[WS_ALPHA + t * NC + c] = __expf(log_alpha[t * NC + c]);
    if (act) {
        float m2 = 0.0f;
        #pragma unroll
        for (int jj = 0; jj < DIM; ++jj)
            m2 = fmaf(B[i * 16 + jj], mean[c * DIM + jj], m2);
        ws[WS_MU2 + c * 16 + i] = m2;
    }
}

// R9 structure + 2 samples/thread: the per-layer serial chain
// (r2-reduce -> v_sqrt -> v_rcp -> 2x v_log) is ~60-80 cyc of latency in
// which a single chain can't issue; interleaving two independent samples
// fills those slots from within the wave (R9: VALUBusy 73% — the idle 27%
// is this latency). SGPR param loads amortize over both samples for free.
__global__ void __launch_bounds__(256) density_kernel(
    const float* __restrict__ z, const float* __restrict__ z0,
    const float* __restrict__ beta, const float* __restrict__ ws,
    float* __restrict__ out, int N) {
    __shared__ float tile[128 * 5];
    const int tid = threadIdx.x;
    const int lane = tid & 63;
    const int wv = tid >> 6;                       // 0..3
    const int c = __builtin_amdgcn_readfirstlane(blockIdx.y * 4 + wv);
    const int s0 = blockIdx.x * 128 + lane;
    const int s1 = s0 + 64;
    const int sl0 = s0 < N ? s0 : N - 1;  // clamp; only final store guarded
    const int sl1 = s1 < N ? s1 : N - 1;

    v2f za[8], zb[8];
    {
        const float4* zp = (const float4*)(z + (size_t)sl0 * DIM);
        float4 a0 = zp[0], a1 = zp[1], a2 = zp[2], a3 = zp[3];
        za[0] = (v2f){a0.x, a0.y}; za[1] = (v2f){a0.z, a0.w};
        za[2] = (v2f){a1.x, a1.y}; za[3] = (v2f){a1.z, a1.w};
        za[4] = (v2f){a2.x, a2.y}; za[5] = (v2f){a2.z, a2.w};
        za[6] = (v2f){a3.x, a3.y}; za[7] = (v2f){a3.z, a3.w};
    }
    {
        const float4* zp = (const float4*)(z + (size_t)sl1 * DIM);
        float4 a0 = zp[0], a1 = zp[1], a2 = zp[2], a3 = zp[3];
        zb[0] = (v2f){a0.x, a0.y}; zb[1] = (v2f){a0.z, a0.w};
        zb[2] = (v2f){a1.x, a1.y}; zb[3] = (v2f){a1.z, a1.w};
        zb[4] = (v2f){a2.x, a2.y}; zb[5] = (v2f){a2.z, a2.w};
        zb[6] = (v2f){a3.x, a3.y}; zb[7] = (v2f){a3.z, a3.w};
    }

    float slja = 0.0f, sljb = 0.0f;      // log2-domain accumulators
    #pragma unroll
    for (int l = 0; l < LAYERS; ++l) {
        const v2f* z0p = (const v2f*)(z0 + (l * NC + c) * DIM);  // uniform -> s_load
        float al = ws[WS_ALPHA + l * NC + c];                    // uniform -> s_load
        float b  = beta[l * NC + c];                             // uniform -> s_load
        v2f da[8], db[8];
        v2f ra0 = (v2f){0.f, 0.f}, ra1 = (v2f){0.f, 0.f};
        v2f rb0 = (v2f){0.f, 0.f}, rb1 = (v2f){0.f, 0.f};
        #pragma unroll
        for (int k = 0; k < 8; ++k) {
            da[k] = za[k] - z0p[k];
            db[k] = zb[k] - z0p[k];
            if (k & 1) { ra1 = __builtin_elementwise_fma(da[k], da[k], ra1);
                         rb1 = __builtin_elementwise_fma(db[k], db[k], rb1); }
            else       { ra0 = __builtin_elementwise_fma(da[k], da[k], ra0);
                         rb0 = __builtin_elementwise_fma(db[k], db[k], rb0); }
        }
        v2f rav = ra0 + ra1, rbv = rb0 + rb1;
        float ra = __builtin_amdgcn_sqrtf(rav.x + rav.y);
        float rb = __builtin_amdgcn_sqrtf(rbv.x + rbv.y);
        float ha = __builtin_amdgcn_rcpf(al + ra);
        float hb = __builtin_amdgcn_rcpf(al + rb);
        float bha = b * ha, bhb = b * hb;
        v2f bha2 = (v2f){bha, bha}, bhb2 = (v2f){bhb, bhb};
        #pragma unroll
        for (int k = 0; k < 8; ++k) {
            za[k] = __builtin_elementwise_fma(bha2, da[k], za[k]);
            zb[k] = __builtin_elementwise_fma(bhb2, db[k], zb[k]);
        }
        float t2a = fmaf(-(b * ra * ha), ha, bha);   // bh - b*r*h*h
        float t2b = fmaf(-(b * rb * hb), hb, bhb);
        float lga = __builtin_amdgcn_logf(1.0f + bha);
        float lgb = __builtin_amdgcn_logf(1.0f + bhb);
        float lta = __builtin_amdgcn_logf(1.0f + t2a);
        float ltb = __builtin_amdgcn_logf(1.0f + t2b);
        slja = fmaf(15.0f, lga, slja) + lta;
        sljb = fmaf(15.0f, lgb, sljb) + ltb;
    }

    // q = || Linv_c*zk - mu2_c ||^2 for both samples (shared SGPR rows).
    const v2f* Li2 = (const v2f*)(ws + WS_LINV + c * 256);  // row i: Li2[i*8+jj]
    const float* m2 = ws + WS_MU2 + c * 16;
    float qa = 0.0f, qb = 0.0f;
    #pragma unroll
    for (int i = 0; i < DIM; ++i) {
        v2f aa = (v2f){0.f, 0.f}, ab = (v2f){0.f, 0.f};
        #pragma unroll
        for (int jj = 0; jj <= (i >> 1); ++jj) {
            aa = __builtin_elementwise_fma(Li2[i * 8 + jj], za[jj], aa);
            ab = __builtin_elementwise_fma(Li2[i * 8 + jj], zb[jj], ab);
        }
        float fa = (aa.x + aa.y) - m2[i];
        float fb = (ab.x + ab.y) - m2[i];
        qa = fmaf(fa, fa, qa);
        qb = fmaf(fb, fb, qb);
    }

    const float ln2 = 0.6931471805599453f;
    float cst = ws[WS_CST + c];
    float resa = cst + fmaf(-0.5f, qa, slja * ln2);
    float resb = cst + fmaf(-0.5f, qb, sljb * ln2);
    if (resa != resa) resa = -INFINITY;  // NaN -> -inf (reference semantics)
    if (resb != resb) resb = -INFINITY;

    // Transpose through LDS (4-c group) for merged stores.
    tile[lane * 5 + wv] = resa;
    tile[(lane + 64) * 5 + wv] = resb;
    __syncthreads();
    #pragma unroll
    for (int half = 0; half < 2; ++half) {
        const int idx = tid + half * 256;
        const int srow = idx >> 2, col = idx & 3;
        const int gs = blockIdx.x * 128 + srow;
        if (gs < N) out[(size_t)gs * NC + blockIdx.y * 4 + col] = tile[srow * 5 + col];
    }
}

extern "C" void kernel_launch(void* const* d_in, const int* in_sizes, int n_in,
                              void* d_out, int out_size, void* d_ws, size_t ws_size,
                              hipStream_t stream) {
    const float* z    = (const float*)d_in[0];
    const float* z0   = (const float*)d_in[1];
    const float* la   = (const float*)d_in[2];
    const float* beta = (const float*)d_in[3];
    const float* mean = (const float*)d_in[4];
    const float* cov  = (const float*)d_in[5];
    float* out = (float*)d_out;
    float* ws  = (float*)d_ws;
    const int N = in_sizes[0] / DIM;

    hipLaunchKernelGGL(prep_kernel, dim3(NC), dim3(64), 0, stream, cov, la, mean, ws);
    const int nb = (N + 127) / 128;
    hipLaunchKernelGGL(density_kernel, dim3(nb, 4), dim3(256), 0, stream,
                       z, z0, beta, ws, out, N);
}

// Round 11
// 116.132 us; speedup vs baseline: 1.0778x; 1.0778x over previous
//
#include <hip/hip_runtime.h>
#include <math.h>

#define NC 16
#define DIM 16
#define LAYERS 6

typedef float v2f __attribute__((ext_vector_type(2)));

// ws layout (floats)
#define WS_LINV  0      // [NC][DIM][DIM] row-major, zeros above diag, 4096
#define WS_CST   4096   // [NC], 16
#define WS_ALPHA 4112   // [L][NC] = exp(log_alpha), 96
#define WS_DZ0   4208   // [L][NC][DIM]: z0_l - z0_{l+1} (l<5), z0_5 - mean (l=5)
#define WS_TOT   5744

// One block per component, one wave per block.
__global__ void __launch_bounds__(64) prep_kernel(
    const float* __restrict__ cov, const float* __restrict__ log_alpha,
    const float* __restrict__ z0, const float* __restrict__ mean,
    float* __restrict__ ws) {
    __shared__ float A[DIM * 17];     // padded: A[i][j] at i*17+j
    const int c = blockIdx.x;
    const int t = threadIdx.x;        // 0..63
    for (int k = t; k < DIM * DIM; k += 64) {
        int r = k >> 4, j = k & 15;
        A[r * 17 + j] = cov[c * 256 + k];
    }
    __syncthreads();
    const int i = t & 15;
    const bool act = t < 16;
    for (int k = 0; k < DIM; ++k) {
        if (act && i == k) A[k * 17 + k] = sqrtf(A[k * 17 + k]);
        __syncthreads();
        if (act && i > k) A[i * 17 + k] /= A[k * 17 + k];
        __syncthreads();
        if (act && i > k) {
            float lik = A[i * 17 + k];
            for (int j2 = k + 1; j2 <= i; ++j2)
                A[i * 17 + j2] -= lik * A[j2 * 17 + k];
        }
        __syncthreads();
    }
    // Forward substitution for column j of Linv — fully unrolled (VGPRs).
    const int j = i;
    float x[DIM];
    #pragma unroll
    for (int r = 0; r < DIM; ++r) {
        float s = (r == j) ? 1.0f : 0.0f;
        #pragma unroll
        for (int k = 0; k < r; ++k) s = fmaf(-A[r * 17 + k], x[k], s);
        x[r] = s / A[r * 17 + r];
    }
    if (act) {
        #pragma unroll
        for (int r = 0; r < DIM; ++r)
            ws[WS_LINV + c * 256 + r * 16 + j] = x[r];   // 0 above diag
    }
    if (t == 0) {
        float hld = 0.0f;
        #pragma unroll
        for (int r = 0; r < DIM; ++r) hld += __logf(A[r * 17 + r]);
        const float log2pi = 1.8378770664093453f;
        ws[WS_CST + c] = -0.5f * (float)DIM * log2pi - hld;
    }
    if (t < LAYERS) ws[WS_ALPHA + t * NC + c] = __expf(log_alpha[t * NC + c]);
    // dz0[l][c][i]: the d-state recurrence constant.
    if (act) {
        #pragma unroll
        for (int l = 0; l < LAYERS; ++l) {
            float cur = z0[(l * NC + c) * DIM + i];
            float nxt = (l < LAYERS - 1) ? z0[((l + 1) * NC + c) * DIM + i]
                                         : mean[c * DIM + i];
            ws[WS_DZ0 + (l * NC + c) * DIM + i] = cur - nxt;
        }
    }
}

// d-state recurrence: with d_l = zc_l - z0_l,
//   d_{l+1} = (1+bh_l)*d_l + (z0_l - z0_{l+1})
// — ONE pk-fma per pair per layer instead of sub+update (16 pk vs 24 pk),
// and d_6 = zc_6 - mean feeds the matvec directly (mu2 eliminated).
// Grid is linearized so the 4 c-group blocks of one sample tile are
// dispatch-adjacent -> co-resident -> z served from L2 after first read.
__global__ void __launch_bounds__(256) density_kernel(
    const float* __restrict__ z, const float* __restrict__ z0,
    const float* __restrict__ beta, const float* __restrict__ ws,
    float* __restrict__ out, int N) {
    __shared__ float tile[64 * 5];
    const int tid = threadIdx.x;
    const int lane = tid & 63;
    const int wv = tid >> 6;                       // 0..3
    const int xb = blockIdx.x >> 2;                // sample tile
    const int cg = blockIdx.x & 3;                 // c-group
    const int c = __builtin_amdgcn_readfirstlane(cg * 4 + wv);
    const int s = xb * 64 + lane;
    const int sl = s < N ? s : N - 1;    // clamp; only final store is guarded

    // d_0 = z - z0_0
    v2f d2[8];
    {
        const float4* zp = (const float4*)(z + (size_t)sl * DIM);
        const v2f* z0p = (const v2f*)(z0 + c * DIM);         // layer 0, uniform
        float4 a0 = zp[0], a1 = zp[1], a2 = zp[2], a3 = zp[3];
        d2[0] = (v2f){a0.x, a0.y} - z0p[0]; d2[1] = (v2f){a0.z, a0.w} - z0p[1];
        d2[2] = (v2f){a1.x, a1.y} - z0p[2]; d2[3] = (v2f){a1.z, a1.w} - z0p[3];
        d2[4] = (v2f){a2.x, a2.y} - z0p[4]; d2[5] = (v2f){a2.z, a2.w} - z0p[5];
        d2[6] = (v2f){a3.x, a3.y} - z0p[6]; d2[7] = (v2f){a3.z, a3.w} - z0p[7];
    }

    float slj2 = 0.0f;                   // log2-domain accumulator
    #pragma unroll
    for (int l = 0; l < LAYERS; ++l) {
        v2f r2a = (v2f){0.f, 0.f}, r2b = (v2f){0.f, 0.f};
        #pragma unroll
        for (int k = 0; k < 8; ++k) {
            if (k & 1) r2b = __builtin_elementwise_fma(d2[k], d2[k], r2b);
            else       r2a = __builtin_elementwise_fma(d2[k], d2[k], r2a);
        }
        v2f r2v = r2a + r2b;
        float r = __builtin_amdgcn_sqrtf(r2v.x + r2v.y);  // raw v_sqrt_f32
        float al = ws[WS_ALPHA + l * NC + c];             // uniform -> s_load
        float b  = beta[l * NC + c];                      // uniform -> s_load
        float h  = __builtin_amdgcn_rcpf(al + r);
        float bh = b * h;
        float g  = 1.0f + bh;
        float t2 = fmaf(-(b * r * h), h, bh);             // bh - b*r*h*h
        float lg = __builtin_amdgcn_logf(g);
        float lt = __builtin_amdgcn_logf(1.0f + t2);
        slj2 = fmaf(15.0f, lg, slj2) + lt;
        // d <- g*d + dz0_l   (dz0 uniform -> s_load)
        const v2f* dz = (const v2f*)(ws + WS_DZ0 + (l * NC + c) * DIM);
        v2f g2 = (v2f){g, g};
        #pragma unroll
        for (int k = 0; k < 8; ++k)
            d2[k] = __builtin_elementwise_fma(g2, d2[k], dz[k]);
    }

    // q = || Linv_c * d ||^2  (d = zc_6 - mean), packed over j.
    const v2f* Li2 = (const v2f*)(ws + WS_LINV + c * 256);  // row i: Li2[i*8+jj]
    float q = 0.0f;
    #pragma unroll
    for (int i = 0; i < DIM; ++i) {
        v2f acc2 = (v2f){0.f, 0.f};
        #pragma unroll
        for (int jj = 0; jj <= (i >> 1); ++jj)
            acc2 = __builtin_elementwise_fma(Li2[i * 8 + jj], d2[jj], acc2);
        float acc = acc2.x + acc2.y;
        q = fmaf(acc, acc, q);
    }

    const float ln2 = 0.6931471805599453f;
    float res = ws[WS_CST + c] + fmaf(-0.5f, q, slj2 * ln2);
    if (res != res) res = -INFINITY;     // NaN -> -inf (reference semantics)

    // Transpose through LDS (4-c group) for merged stores.
    tile[lane * 5 + wv] = res;
    __syncthreads();
    const int srow = tid >> 2, col = tid & 3;
    const int gs = xb * 64 + srow;
    if (gs < N) out[(size_t)gs * NC + cg * 4 + col] = tile[srow * 5 + col];
}

extern "C" void kernel_launch(void* const* d_in, const int* in_sizes, int n_in,
                              void* d_out, int out_size, void* d_ws, size_t ws_size,
                              hipStream_t stream) {
    const float* z    = (const float*)d_in[0];
    const float* z0   = (const float*)d_in[1];
    const float* la   = (const float*)d_in[2];
    const float* beta = (const float*)d_in[3];
    const float* mean = (const float*)d_in[4];
    const float* cov  = (const float*)d_in[5];
    float* out = (float*)d_out;
    float* ws  = (float*)d_ws;
    const int N = in_sizes[0] / DIM;

    hipLaunchKernelGGL(prep_kernel, dim3(NC), dim3(64), 0, stream, cov, la, z0, mean, ws);
    const int nb = (N + 63) / 64;
    hipLaunchKernelGGL(density_kernel, dim3(nb * 4), dim3(256), 0, stream,
                       z, z0, beta, ws, out, N);
}